// Round 16
// baseline (239.689 us; speedup 1.0000x reference)
//
#include <hip/hip_runtime.h>
#include <hip/hip_bf16.h>
#include <hip/hip_cooperative_groups.h>
#include <stdint.h>

namespace cg = cooperative_groups;

typedef __attribute__((ext_vector_type(8))) short bf16x8;
typedef __attribute__((ext_vector_type(4))) float f32x4;
typedef __attribute__((ext_vector_type(8))) unsigned short u16x8;

__device__ __forceinline__ unsigned short f2bf(float f) {
  unsigned int u = __float_as_uint(f);
  u = u + 0x7fffu + ((u >> 16) & 1u);   // RNE
  return (unsigned short)(u >> 16);
}

// ---------------- prep kernels (r13-proven versions) ----------------
// blocks [0,1152): wp[kk][cb][o][64ci] = bf16(w) transposed + swizzled (batch-independent)
// blocks [1152,1160): style modulation s[b][c]
// blocks [1160,2184): wsq[o][ci] = sum_k w^2
__global__ void k1(const float* __restrict__ w, const float* __restrict__ style,
                   const float* __restrict__ mw, const float* __restrict__ mb,
                   unsigned short* __restrict__ wp, float* __restrict__ s,
                   float* __restrict__ wsq) {
  const int bid = blockIdx.x, t = threadIdx.x;
  if (bid < 1152) {
    const int id = bid * 256 + t;
    const int c8 = id & 7, o = (id >> 3) & 511, cb = (id >> 12) & 7, kk = id >> 15;
    const int ci0 = cb*64 + c8*8;
    u16x8 h;
    #pragma unroll
    for (int e = 0; e < 8; ++e) h[e] = f2bf(w[((size_t)(o*512 + ci0 + e))*9 + kk]);
    char* base = (char*)wp + (((size_t)kk*8 + cb)*512 + o)*128
               + ((unsigned)(c8*16) ^ (unsigned)((o & 7) << 4));
    *(u16x8*)base = h;
  } else if (bid < 1160) {
    __shared__ float st[512];
    const int b = bid - 1152;
    st[t]       = style[b*512 + t];
    st[t + 256] = style[b*512 + t + 256];
    __syncthreads();
    for (int k = 0; k < 2; ++k) {
      int c = t + k*256;
      const float* row = mw + (size_t)c * 512;
      float acc = 0.f;
      for (int j = 0; j < 512; ++j) acc += st[j] * row[j];
      s[b*512 + c] = acc * 0.04419417382415922f + mb[c];  // 1/sqrt(512)
    }
  } else {
    int g = (bid - 1160) * 256 + t;     // o*512+ci
    const float* p = w + (size_t)g * 9;
    float acc = 0.f;
    #pragma unroll
    for (int q = 0; q < 9; ++q) { float v = p[q]; acc += v*v; }
    wsq[g] = acc;
  }
}

// dm[b][o] = cs * rsqrt(cs^2 * sum_ci s^2 * wsq + 1e-8)   (cs folded for epilogue)
__global__ void k_demod(const float* __restrict__ s, const float* __restrict__ wsq,
                        float* __restrict__ dm) {
  __shared__ float s2[512];
  const int g = blockIdx.x * 256 + threadIdx.x;
  const int b = g >> 9, o = g & 511, t = threadIdx.x;
  float v0 = s[b*512 + t], v1 = s[b*512 + t + 256];
  s2[t] = v0*v0; s2[t+256] = v1*v1;
  __syncthreads();
  const float* row = wsq + (size_t)o * 512;
  float acc = 0.f;
  for (int j = 0; j < 512; ++j) acc += s2[j] * row[j];
  dm[g] = 0.014731391274719739f * rsqrtf(acc * (1.0f/4608.0f) + 1e-8f);
}

// ---------------- fused conv kernel (cooperative) ----------------
// Phase A (pre): each block converts its (b, pt, 4-cb half) slice of input into
//   ib[b][cb][y][x][64ci] (r14 LDS-transpose body, staged in ldsA). ot=0 -> cb 0-3,
//   ot=1 -> cb 4-7: exact cover. b = wg&7 pins writers AND readers of ib[b] to one
//   XCD -> ib stays L2-local; no HBM round-trip, no kernel boundary drain.
// grid.sync(), then Phase B = rounds 11-15 conv verbatim (128.3us, MfmaUtil 51-53%).
__global__ __launch_bounds__(512, 2) void k_conv(const float* __restrict__ in,
                                                 const float* __restrict__ s,
                                                 const unsigned short* __restrict__ wp,
                                                 const float* __restrict__ dm,
                                                 unsigned short* ib,
                                                 float* __restrict__ out) {
  __shared__ __align__(16) unsigned char ldsA[3*32768];
  __shared__ __align__(16) unsigned char ldsB[49152];

  const int tid = threadIdx.x;
  const int lan15 = tid & 15;
  const int lgrp = (tid >> 4) & 3;
  const int wid = tid >> 6;
  const int wm = wid >> 2, wn = wid & 3;
  const unsigned wg = blockIdx.x;
  const int b = wg & 7, pt = (wg >> 3) & 15, ot = (wg >> 7) & 1;   // batch b -> one XCD
  const int o0 = ot * 256, y0 = pt * 4;

  // ---------- Phase A: input -> ib (this block's 4 rows, 4 cb groups) ----------
  {
    const int x = tid & 63, c8 = tid >> 6;
    const int rx = tid >> 3, rc = tid & 7;
    const unsigned so = (unsigned)(x*128)  + (((unsigned)(c8*16)) ^ ((unsigned)(x  & 7) << 4));
    const unsigned ro = (unsigned)(rx*128) + (((unsigned)(rc*16)) ^ ((unsigned)(rx & 7) << 4));
    #pragma unroll
    for (int q = 0; q < 4; ++q) {
      const int cb = ot*4 + q;
      const int ci0 = cb*64 + c8*8;
      f32x4 s0 = *(const f32x4*)(s + b*512 + ci0);
      f32x4 s1 = *(const f32x4*)(s + b*512 + ci0 + 4);
      const float* p = in + (((size_t)b*512 + ci0) * 64 + y0) * 64 + x;
      u16x8 h[4];
      #pragma unroll
      for (int j = 0; j < 4; ++j) {
        #pragma unroll
        for (int e = 0; e < 4; ++e) h[j][e]     = f2bf(p[(size_t)e*4096 + j*64] * s0[e]);
        #pragma unroll
        for (int e = 0; e < 4; ++e) h[j][e + 4] = f2bf(p[(size_t)(e+4)*4096 + j*64] * s1[e]);
      }
      #pragma unroll
      for (int j = 0; j < 4; ++j)
        *(u16x8*)(ldsA + j*8192 + so) = h[j];
      __syncthreads();
      unsigned short* dst = ib + (((size_t)(b*8 + cb)*64 + y0) * 4096) + tid*8;
      #pragma unroll
      for (int j = 0; j < 4; ++j)
        *(u16x8*)(dst + j*4096) = *(const u16x8*)(ldsA + j*8192 + ro);
      __syncthreads();
    }
  }
  cg::this_grid().sync();

  // ---------- Phase B: conv (verbatim) ----------
  const unsigned short* ibb = ib + (size_t)b * 8 * 64 * 64 * 64;

  auto stageA = [&](int tap, int cbb, int buf) {
    const char* src = (const char*)(wp + (((size_t)tap*8 + cbb)*512 + (size_t)o0) * 64);
    unsigned char* dst = ldsA + buf*32768;
    #pragma unroll
    for (int r = 0; r < 4; ++r) {
      __builtin_amdgcn_global_load_lds(
        (const __attribute__((address_space(1))) unsigned int*)(src + tid*16 + r*8192),
        (__attribute__((address_space(3))) unsigned int*)(dst + tid*16 + r*8192),
        16, 0, 0);
    }
  };

  u16x8 bv[6];
  auto loadB = [&](int cbb) {           // 6 x 16B loads/thread (rows clamped)
    const int c8 = tid & 7, x = (tid >> 3) & 63;
    const unsigned short* base = ibb + ((size_t)cbb * 64 * 64 + (size_t)x) * 64 + c8*8;
    #pragma unroll
    for (int j = 0; j < 6; ++j) {
      const int yi = y0 - 1 + j;
      const int yc = yi < 0 ? 0 : (yi > 63 ? 63 : yi);
      bv[j] = *(const u16x8*)(base + (size_t)yc * 4096);
    }
  };
  auto writeB = [&]() {
    const int c8 = tid & 7, x = (tid >> 3) & 63;
    const unsigned off = (unsigned)(x*128) + (((unsigned)(c8*16)) ^ ((unsigned)(x & 7) << 4));
    #pragma unroll
    for (int j = 0; j < 6; ++j) {
      const int yi = y0 - 1 + j;
      const bool valid = (yi >= 0) & (yi < 64);
      u16x8 v = valid ? bv[j] : (u16x8){0,0,0,0,0,0,0,0};
      *(u16x8*)(ldsB + j*8192 + off) = v;
    }
  };

  f32x4 acc[8][4];
  #pragma unroll
  for (int mf = 0; mf < 8; ++mf)
    #pragma unroll
    for (int nf = 0; nf < 4; ++nf)
      acc[mf][nf] = (f32x4){0.f, 0.f, 0.f, 0.f};

  const int aB0 = (wm*128 + lan15)*128 + ((lgrp*16) ^ ((lan15 & 7) << 4));
  const int aB1 = aB0 ^ 64;
  int cB0[3], cB1[3];
  #pragma unroll
  for (int kx = 0; kx < 3; ++kx) {
    const int x0 = lan15 + kx - 1;
    cB0[kx] = wn*8192 + x0*128 + ((lgrp*16) ^ ((x0 & 7) << 4));
    cB1[kx] = cB0[kx] ^ 64;
  }
  const bool zL = (lan15 == 0), zR = (lan15 == 15);

#define BARR asm volatile("s_barrier" ::: "memory")
#define GATE(N) asm volatile("s_waitcnt vmcnt(" #N ")\n\ts_barrier" ::: "memory")

#define RD_A(MH, KS) _Pragma("unroll") \
    for (int i = 0; i < 4; ++i) \
      af[i] = *(const bf16x8*)(Ab + ((KS) ? aB1 : aB0) + ((MH)*4 + i)*2048);

#define RD_B(KS) _Pragma("unroll") \
    for (int nf = 0; nf < 4; ++nf) { \
      bf16x8 v = *(const bf16x8*)(Bb + ((KS) ? cB1[kx_] : cB0[kx_]) + nf*2048); \
      if (kx_ == 0 && nf == 0) { if (zL) v = (bf16x8){0,0,0,0,0,0,0,0}; } \
      if (kx_ == 2 && nf == 3) { if (zR) v = (bf16x8){0,0,0,0,0,0,0,0}; } \
      bfr[nf] = v; }

#define MF16(MH) { __builtin_amdgcn_s_setprio(1); \
    _Pragma("unroll") for (int i = 0; i < 4; ++i) \
      _Pragma("unroll") for (int nf = 0; nf < 4; ++nf) \
        acc[(MH)*4+i][nf] = __builtin_amdgcn_mfma_f32_16x16x32_bf16(af[i], bfr[nf], acc[(MH)*4+i][nf], 0, 0, 0); \
    __builtin_amdgcn_s_setprio(0); }

// 4 barrier intervals: {rdA0,rdB0 | MF0 rdA1 | MF1 rdA0' rdB1 | MF0' rdA1' | MF1'}
#define PH4 \
    RD_A(0,0) RD_B(0) MF16(0) \
    RD_A(1,0) BARR; MF16(1) \
    RD_A(0,1) RD_B(1) BARR; MF16(0) \
    RD_A(1,1) BARR; MF16(1)

#define TAP(KK) { \
    constexpr int ky_ = (KK)/3, kx_ = (KK)%3; \
    const unsigned char* Ab = ldsA + ((KK)%3)*32768; \
    const unsigned char* Bb = ldsB + ky_*8192; \
    bf16x8 af[4], bfr[4]; \
    stageA((KK)+2, cb, ((KK)+2)%3); \
    GATE(8); \
    PH4 }

  // prologue: B0 loads, A0+A1 in flight, write B0, gated barrier.
  loadB(0);
  asm volatile("" ::: "memory");
  stageA(0, 0, 0);
  stageA(1, 0, 1);
  asm volatile("s_waitcnt vmcnt(8)" ::: "memory");   // B(6) done; A0/A1 in flight
  writeB();
  asm volatile("s_waitcnt vmcnt(4) lgkmcnt(0)\n\ts_barrier" ::: "memory");  // A0 done

  for (int cb = 0; cb < 7; ++cb) {
    TAP(0) TAP(1) TAP(2) TAP(3) TAP(4) TAP(5) TAP(6)
    { // kk == 7: stage A(next-cb,0), gate, issue B loads, phases
      constexpr int ky_ = 2, kx_ = 1;
      const unsigned char* Ab = ldsA + (7%3)*32768;
      const unsigned char* Bb = ldsB + ky_*8192;
      bf16x8 af[4], bfr[4];
      stageA(0, cb + 1, 0);
      GATE(8);
      loadB(cb + 1);
      PH4
    }
    { // kk == 8: drain (B + A(8)), stage A(next,1), phases, boundary write
      asm volatile("s_waitcnt vmcnt(0)" ::: "memory");
      stageA(1, cb + 1, 1);
      constexpr int ky_ = 2, kx_ = 2;
      const unsigned char* Ab = ldsA + (8%3)*32768;
      const unsigned char* Bb = ldsB + ky_*8192;
      bf16x8 af[4], bfr[4];
      PH4
      BARR;                                          // all waves done reading B(cb)
      writeB();
      asm volatile("s_waitcnt lgkmcnt(0)\n\ts_barrier" ::: "memory");
    }
  }
  { // cb == 7 tail
    const int cb = 7;
    TAP(0) TAP(1) TAP(2) TAP(3) TAP(4) TAP(5) TAP(6)
    { // kk == 7: no staging left; gate on A(8) in flight
      constexpr int ky_ = 2, kx_ = 1;
      const unsigned char* Ab = ldsA + (7%3)*32768;
      const unsigned char* Bb = ldsB + ky_*8192;
      bf16x8 af[4], bfr[4];
      GATE(4);
      PH4
    }
    { // kk == 8: final drain
      asm volatile("s_waitcnt vmcnt(0)" ::: "memory");
      constexpr int ky_ = 2, kx_ = 2;
      const unsigned char* Ab = ldsA + (8%3)*32768;
      const unsigned char* Bb = ldsB + ky_*8192;
      bf16x8 af[4], bfr[4];
      PH4
    }
  }

  // epilogue: scale by cs*demod[b][o], fenced per-mf (one d4 live at a time)
  const float* dmb = dm + b*512;
  float* outb = out + (size_t)b * 512 * 4096;
  #pragma unroll
  for (int mf = 0; mf < 8; ++mf) {
    asm volatile("" ::: "memory");     // pin d4 load into this iteration
    const int o = o0 + wm*128 + mf*16 + lgrp*4;
    const f32x4 d4 = *(const f32x4*)(dmb + o);
    #pragma unroll
    for (int nf = 0; nf < 4; ++nf) {
      const int p = pt*256 + wn*64 + nf*16 + lan15;
      #pragma unroll
      for (int r = 0; r < 4; ++r)
        outb[(size_t)(o + r) * 4096 + p] = acc[mf][nf][r] * d4[r];
    }
  }
#undef TAP
#undef PH4
#undef MF16
#undef RD_B
#undef RD_A
#undef GATE
#undef BARR
}

extern "C" void kernel_launch(void* const* d_in, const int* in_sizes, int n_in,
                              void* d_out, int out_size, void* d_ws, size_t ws_size,
                              hipStream_t stream) {
  const float* input  = (const float*)d_in[0];
  const float* style  = (const float*)d_in[1];
  const float* weight = (const float*)d_in[2];
  const float* mw     = (const float*)d_in[3];
  const float* mb     = (const float*)d_in[4];
  float* out = (float*)d_out;
  char* ws = (char*)d_ws;
  float* s     = (float*)ws;                              // 16 KB
  float* dm    = (float*)(ws + 16384);                    // 16 KB
  float* wsq   = (float*)(ws + 32768);                    // 1 MB
  unsigned short* wp = (unsigned short*)(ws + 1081344);   // 4.7 MB (batch-independent)
  unsigned short* ib = (unsigned short*)(ws + 5799936);   // 33.6 MB (bf16 s*input, L2-local)

  hipLaunchKernelGGL(k1,      dim3(2184), dim3(256), 0, stream, weight, style, mw, mb, wp, s, wsq);
  hipLaunchKernelGGL(k_demod, dim3(16),   dim3(256), 0, stream, s, wsq, dm);

  void* args[] = {(void*)&input, (void*)&s, (void*)&wp, (void*)&dm, (void*)&ib, (void*)&out};
  hipLaunchCooperativeKernel((const void*)k_conv, dim3(256), dim3(512), args, 0, stream);
}

// Round 18
// 204.302 us; speedup vs baseline: 1.1732x; 1.1732x over previous
//
#include <hip/hip_runtime.h>
#include <hip/hip_bf16.h>
#include <stdint.h>

typedef __attribute__((ext_vector_type(8))) short bf16x8;
typedef __attribute__((ext_vector_type(4))) float f32x4;
typedef __attribute__((ext_vector_type(16))) float f32x16;
typedef __attribute__((ext_vector_type(8))) unsigned short u16x8;

__device__ __forceinline__ unsigned short f2bf(float f) {
  unsigned int u = __float_as_uint(f);
  u = u + 0x7fffu + ((u >> 16) & 1u);   // RNE
  return (unsigned short)(u >> 16);
}

// ---------------- prep kernels (r13 verbatim) ----------------
__global__ void k1(const float* __restrict__ w, const float* __restrict__ style,
                   const float* __restrict__ mw, const float* __restrict__ mb,
                   unsigned short* __restrict__ wp, float* __restrict__ s,
                   float* __restrict__ wsq) {
  const int bid = blockIdx.x, t = threadIdx.x;
  if (bid < 1152) {
    const int id = bid * 256 + t;
    const int c8 = id & 7, o = (id >> 3) & 511, cb = (id >> 12) & 7, kk = id >> 15;
    const int ci0 = cb*64 + c8*8;
    u16x8 h;
    #pragma unroll
    for (int e = 0; e < 8; ++e) h[e] = f2bf(w[((size_t)(o*512 + ci0 + e))*9 + kk]);
    char* base = (char*)wp + (((size_t)kk*8 + cb)*512 + o)*128
               + ((unsigned)(c8*16) ^ (unsigned)((o & 7) << 4));
    *(u16x8*)base = h;
  } else if (bid < 1160) {
    __shared__ float st[512];
    const int b = bid - 1152;
    st[t]       = style[b*512 + t];
    st[t + 256] = style[b*512 + t + 256];
    __syncthreads();
    for (int k = 0; k < 2; ++k) {
      int c = t + k*256;
      const float* row = mw + (size_t)c * 512;
      float acc = 0.f;
      for (int j = 0; j < 512; ++j) acc += st[j] * row[j];
      s[b*512 + c] = acc * 0.04419417382415922f + mb[c];  // 1/sqrt(512)
    }
  } else {
    int g = (bid - 1160) * 256 + t;     // o*512+ci
    const float* p = w + (size_t)g * 9;
    float acc = 0.f;
    #pragma unroll
    for (int q = 0; q < 9; ++q) { float v = p[q]; acc += v*v; }
    wsq[g] = acc;
  }
}

__global__ void k_demod(const float* __restrict__ s, const float* __restrict__ wsq,
                        float* __restrict__ dm) {
  __shared__ float s2[512];
  const int g = blockIdx.x * 256 + threadIdx.x;
  const int b = g >> 9, o = g & 511, t = threadIdx.x;
  float v0 = s[b*512 + t], v1 = s[b*512 + t + 256];
  s2[t] = v0*v0; s2[t+256] = v1*v1;
  __syncthreads();
  const float* row = wsq + (size_t)o * 512;
  float acc = 0.f;
  for (int j = 0; j < 512; ++j) acc += s2[j] * row[j];
  dm[g] = 0.014731391274719739f * rsqrtf(acc * (1.0f/4608.0f) + 1e-8f);
}

__global__ void k_inprep(const float* __restrict__ in, const float* __restrict__ s,
                         unsigned short* __restrict__ ib) {
  __shared__ __align__(16) unsigned char lds[8192];
  const int tid = threadIdx.x;
  const int x = tid & 63, c8 = tid >> 6;
  const int y = blockIdx.x, cb = blockIdx.y, b = blockIdx.z;
  const int ci0 = cb*64 + c8*8;
  f32x4 s0 = *(const f32x4*)(s + b*512 + ci0);
  f32x4 s1 = *(const f32x4*)(s + b*512 + ci0 + 4);
  const float* p = in + (((size_t)b*512 + ci0) * 64 + y) * 64 + x;
  u16x8 h;
  #pragma unroll
  for (int e = 0; e < 4; ++e) h[e]     = f2bf(p[(size_t)e * 4096] * s0[e]);
  #pragma unroll
  for (int e = 0; e < 4; ++e) h[e + 4] = f2bf(p[(size_t)(e + 4) * 4096] * s1[e]);
  *(u16x8*)(lds + x*128 + (((unsigned)(c8*16)) ^ ((unsigned)(x & 7) << 4))) = h;
  __syncthreads();
  const int rx = tid >> 3, rc = tid & 7;
  u16x8 v = *(const u16x8*)(lds + rx*128 + (((unsigned)(rc*16)) ^ ((unsigned)(rx & 7) << 4)));
  unsigned short* dst = ib + (((size_t)(b*8 + cb)*64 + y) * 4096) + tid*8;
  *(u16x8*)dst = v;
}

// ---------------- conv kernel: 32x32x16 MFMA (B-offset fold FIXED) ----------------
// r17 bug: B column clamped BEFORE adding nf*32 -> (kx=0,nf=1,l31=0) read col 32
// instead of col 31. Fix: x0 = nf*32 + l31 + kx - 1, clamp, per-(kx,nf) base+key.
// C/D layout m74/m101-verified: col=l&31, row=(reg&3)+8*(reg>>2)+4*(l>>5).
__global__ __launch_bounds__(512, 2) void k_conv(const unsigned short* __restrict__ ib,
                                                 const unsigned short* __restrict__ wp,
                                                 const float* __restrict__ dm,
                                                 float* __restrict__ out) {
  __shared__ __align__(16) unsigned char ldsA[3*32768];
  __shared__ __align__(16) unsigned char ldsB[49152];

  const int tid = threadIdx.x;
  const int l31 = tid & 31;
  const int lhi = (tid >> 5) & 1;
  const int wid = tid >> 6;
  const int wm = wid >> 2, wn = wid & 3;
  const unsigned wg = blockIdx.x;
  const int b = wg & 7, pt = (wg >> 3) & 15, ot = (wg >> 7) & 1;   // batch b -> one XCD
  const int o0 = ot * 256, y0 = pt * 4;

  const unsigned short* ibb = ib + (size_t)b * 8 * 64 * 64 * 64;

  auto stageA = [&](int tap, int cbb, int buf) {
    const char* src = (const char*)(wp + (((size_t)tap*8 + cbb)*512 + (size_t)o0) * 64);
    unsigned char* dst = ldsA + buf*32768;
    #pragma unroll
    for (int r = 0; r < 4; ++r) {
      __builtin_amdgcn_global_load_lds(
        (const __attribute__((address_space(1))) unsigned int*)(src + tid*16 + r*8192),
        (__attribute__((address_space(3))) unsigned int*)(dst + tid*16 + r*8192),
        16, 0, 0);
    }
  };

  u16x8 bv[6];
  auto loadB = [&](int cbb) {           // 6 x 16B loads/thread (rows clamped)
    const int c8 = tid & 7, x = (tid >> 3) & 63;
    const unsigned short* base = ibb + ((size_t)cbb * 64 * 64 + (size_t)x) * 64 + c8*8;
    #pragma unroll
    for (int j = 0; j < 6; ++j) {
      const int yi = y0 - 1 + j;
      const int yc = yi < 0 ? 0 : (yi > 63 ? 63 : yi);
      bv[j] = *(const u16x8*)(base + (size_t)yc * 4096);
    }
  };
  auto writeB = [&]() {
    const int c8 = tid & 7, x = (tid >> 3) & 63;
    const unsigned off = (unsigned)(x*128) + (((unsigned)(c8*16)) ^ ((unsigned)(x & 7) << 4));
    #pragma unroll
    for (int j = 0; j < 6; ++j) {
      const int yi = y0 - 1 + j;
      const bool valid = (yi >= 0) & (yi < 64);
      u16x8 v = valid ? bv[j] : (u16x8){0,0,0,0,0,0,0,0};
      *(u16x8*)(ldsB + j*8192 + off) = v;
    }
  };

  f32x16 acc[4][2];
  #pragma unroll
  for (int mf = 0; mf < 4; ++mf)
    #pragma unroll
    for (int nf = 0; nf < 2; ++nf)
      #pragma unroll
      for (int e = 0; e < 16; ++e) acc[mf][nf][e] = 0.f;

  // A: row = wm*128 + i*32 + l31; k-bytes = (ks*32 + lhi*16) ^ ((l31&7)<<4)
  const int aRow = (wm*128 + l31) * 128;
  const int swA = (l31 & 7) << 4;
  const int lhi16 = lhi << 4;
  int koffA[4];
  #pragma unroll
  for (int ks = 0; ks < 4; ++ks) koffA[ks] = (ks*32 + lhi16) ^ swA;
  // B: col = nf*32 + l31 + kx - 1 (clamped AFTER nf-fold -- the r17 fix)
  int cBase[3][2], cKey[3][2];
  #pragma unroll
  for (int kx = 0; kx < 3; ++kx)
    #pragma unroll
    for (int nf = 0; nf < 2; ++nf) {
      const int x0 = nf*32 + l31 + kx - 1;
      const int xc = x0 < 0 ? 0 : (x0 > 63 ? 63 : x0);
      cBase[kx][nf] = wn*8192 + xc*128;
      cKey[kx][nf]  = (xc & 7) << 4;
    }
  const bool zL = (l31 == 0), zR = (l31 == 31);

#define BARR asm volatile("s_barrier" ::: "memory")
#define GATE(N) asm volatile("s_waitcnt vmcnt(" #N ")\n\ts_barrier" ::: "memory")

#define RD_A(KS) _Pragma("unroll") \
    for (int i = 0; i < 4; ++i) \
      af[i] = *(const bf16x8*)(Ab + aRow + i*4096 + koffA[KS]);

#define RD_B(KS) _Pragma("unroll") \
    for (int nf = 0; nf < 2; ++nf) { \
      bf16x8 v = *(const bf16x8*)(Bb + cBase[kx_][nf] + (((KS)*32 + lhi16) ^ cKey[kx_][nf])); \
      if (kx_ == 0 && nf == 0) { if (zL) v = (bf16x8){0,0,0,0,0,0,0,0}; } \
      if (kx_ == 2 && nf == 1) { if (zR) v = (bf16x8){0,0,0,0,0,0,0,0}; } \
      bfr[nf] = v; }

#define MF8 { __builtin_amdgcn_s_setprio(1); \
    _Pragma("unroll") for (int i = 0; i < 4; ++i) \
      _Pragma("unroll") for (int nf = 0; nf < 2; ++nf) \
        acc[i][nf] = __builtin_amdgcn_mfma_f32_32x32x16_bf16(af[i], bfr[nf], acc[i][nf], 0, 0, 0); \
    __builtin_amdgcn_s_setprio(0); }

// 4 k-steps, 3 pacing barriers per tap (mirrors the proven PH4 cadence)
#define PH4 \
    RD_A(0) RD_B(0) MF8 \
    RD_A(1) RD_B(1) BARR; MF8 \
    RD_A(2) RD_B(2) BARR; MF8 \
    RD_A(3) RD_B(3) BARR; MF8

#define TAP(KK) { \
    constexpr int ky_ = (KK)/3, kx_ = (KK)%3; \
    const unsigned char* Ab = ldsA + ((KK)%3)*32768; \
    const unsigned char* Bb = ldsB + ky_*8192; \
    bf16x8 af[4], bfr[2]; \
    stageA((KK)+2, cb, ((KK)+2)%3); \
    GATE(8); \
    PH4 }

  // prologue: B0 loads, A0+A1 in flight, write B0, gated barrier.
  loadB(0);
  asm volatile("" ::: "memory");
  stageA(0, 0, 0);
  stageA(1, 0, 1);
  asm volatile("s_waitcnt vmcnt(8)" ::: "memory");   // B(6) done; A0/A1 in flight
  writeB();
  asm volatile("s_waitcnt vmcnt(4) lgkmcnt(0)\n\ts_barrier" ::: "memory");  // A0 done

  for (int cb = 0; cb < 7; ++cb) {
    TAP(0) TAP(1) TAP(2) TAP(3) TAP(4) TAP(5) TAP(6)
    { // kk == 7: stage A(next-cb,0), gate, issue B loads, phases
      constexpr int ky_ = 2, kx_ = 1;
      const unsigned char* Ab = ldsA + (7%3)*32768;
      const unsigned char* Bb = ldsB + ky_*8192;
      bf16x8 af[4], bfr[2];
      stageA(0, cb + 1, 0);
      GATE(8);
      loadB(cb + 1);
      PH4
    }
    { // kk == 8: drain (B + A(8)), stage A(next,1), phases, boundary write
      asm volatile("s_waitcnt vmcnt(0)" ::: "memory");
      stageA(1, cb + 1, 1);
      constexpr int ky_ = 2, kx_ = 2;
      const unsigned char* Ab = ldsA + (8%3)*32768;
      const unsigned char* Bb = ldsB + ky_*8192;
      bf16x8 af[4], bfr[2];
      PH4
      BARR;                                          // all waves done reading B(cb)
      writeB();
      asm volatile("s_waitcnt lgkmcnt(0)\n\ts_barrier" ::: "memory");
    }
  }
  { // cb == 7 tail
    const int cb = 7;
    TAP(0) TAP(1) TAP(2) TAP(3) TAP(4) TAP(5) TAP(6)
    { // kk == 7: no staging left; gate on A(8) in flight
      constexpr int ky_ = 2, kx_ = 1;
      const unsigned char* Ab = ldsA + (7%3)*32768;
      const unsigned char* Bb = ldsB + ky_*8192;
      bf16x8 af[4], bfr[2];
      GATE(4);
      PH4
    }
    { // kk == 8: final drain
      asm volatile("s_waitcnt vmcnt(0)" ::: "memory");
      constexpr int ky_ = 2, kx_ = 2;
      const unsigned char* Ab = ldsA + (8%3)*32768;
      const unsigned char* Bb = ldsB + ky_*8192;
      bf16x8 af[4], bfr[2];
      PH4
    }
  }

  // epilogue: scale by cs*demod[b][o], fenced per-mf.
  // D row = (reg&3) + 8*(reg>>2) + 4*lhi; col = l31 (+ nf*32).
  const float* dmb = dm + b*512;
  float* outb = out + (size_t)b * 512 * 4096;
  #pragma unroll
  for (int mf = 0; mf < 4; ++mf) {
    asm volatile("" ::: "memory");     // pin dm loads into this iteration
    const int obase = o0 + wm*128 + mf*32;
    #pragma unroll
    for (int q = 0; q < 4; ++q) {
      const int orow = obase + q*8 + lhi*4;
      const f32x4 d4 = *(const f32x4*)(dmb + orow);
      #pragma unroll
      for (int nf = 0; nf < 2; ++nf) {
        const int p = pt*256 + wn*64 + nf*32 + l31;
        #pragma unroll
        for (int r = 0; r < 4; ++r)
          outb[(size_t)(orow + r) * 4096 + p] = acc[mf][nf][q*4 + r] * d4[r];
      }
    }
  }
#undef TAP
#undef PH4
#undef MF8
#undef RD_B
#undef RD_A
#undef GATE
#undef BARR
}

extern "C" void kernel_launch(void* const* d_in, const int* in_sizes, int n_in,
                              void* d_out, int out_size, void* d_ws, size_t ws_size,
                              hipStream_t stream) {
  const float* input  = (const float*)d_in[0];
  const float* style  = (const float*)d_in[1];
  const float* weight = (const float*)d_in[2];
  const float* mw     = (const float*)d_in[3];
  const float* mb     = (const float*)d_in[4];
  float* out = (float*)d_out;
  char* ws = (char*)d_ws;
  float* s     = (float*)ws;                              // 16 KB
  float* dm    = (float*)(ws + 16384);                    // 16 KB
  float* wsq   = (float*)(ws + 32768);                    // 1 MB
  unsigned short* wp = (unsigned short*)(ws + 1081344);   // 4.7 MB (batch-independent)
  unsigned short* ib = (unsigned short*)(ws + 5799936);   // 33.6 MB (pre-scaled bf16 input)

  hipLaunchKernelGGL(k1,       dim3(2184),      dim3(256), 0, stream, weight, style, mw, mb, wp, s, wsq);
  hipLaunchKernelGGL(k_demod,  dim3(16),        dim3(256), 0, stream, s, wsq, dm);
  hipLaunchKernelGGL(k_inprep, dim3(64, 8, 8),  dim3(512), 0, stream, input, s, ib);
  hipLaunchKernelGGL(k_conv,   dim3(256),       dim3(512), 0, stream, ib, wp, dm, out);
}

// Round 19
// 186.545 us; speedup vs baseline: 1.2849x; 1.0952x over previous
//
#include <hip/hip_runtime.h>
#include <hip/hip_bf16.h>
#include <stdint.h>

typedef __attribute__((ext_vector_type(8))) short bf16x8;
typedef __attribute__((ext_vector_type(4))) float f32x4;
typedef __attribute__((ext_vector_type(8))) unsigned short u16x8;

__device__ __forceinline__ unsigned short f2bf(float f) {
  unsigned int u = __float_as_uint(f);
  u = u + 0x7fffu + ((u >> 16) & 1u);   // RNE
  return (unsigned short)(u >> 16);
}

// ---------------- prep kernels ----------------
// blocks [0,1152): wp[kk][cb][o][64ci] = bf16(w) transposed + swizzled (batch-independent)
// blocks [1152,1160): style modulation s[b][c]
// blocks [1160,2184): wsq[o][ci] = sum_k w^2
__global__ void k1(const float* __restrict__ w, const float* __restrict__ style,
                   const float* __restrict__ mw, const float* __restrict__ mb,
                   unsigned short* __restrict__ wp, float* __restrict__ s,
                   float* __restrict__ wsq) {
  const int bid = blockIdx.x, t = threadIdx.x;
  if (bid < 1152) {
    const int id = bid * 256 + t;
    const int c8 = id & 7, o = (id >> 3) & 511, cb = (id >> 12) & 7, kk = id >> 15;
    const int ci0 = cb*64 + c8*8;
    u16x8 h;
    #pragma unroll
    for (int e = 0; e < 8; ++e) h[e] = f2bf(w[((size_t)(o*512 + ci0 + e))*9 + kk]);
    char* base = (char*)wp + (((size_t)kk*8 + cb)*512 + o)*128
               + ((unsigned)(c8*16) ^ (unsigned)((o & 7) << 4));
    *(u16x8*)base = h;
  } else if (bid < 1160) {
    __shared__ float st[512];
    const int b = bid - 1152;
    st[t]       = style[b*512 + t];
    st[t + 256] = style[b*512 + t + 256];
    __syncthreads();
    for (int k = 0; k < 2; ++k) {
      int c = t + k*256;
      const float* row = mw + (size_t)c * 512;
      float acc = 0.f;
      for (int j = 0; j < 512; ++j) acc += st[j] * row[j];
      s[b*512 + c] = acc * 0.04419417382415922f + mb[c];  // 1/sqrt(512)
    }
  } else {
    int g = (bid - 1160) * 256 + t;     // o*512+ci
    const float* p = w + (size_t)g * 9;
    float acc = 0.f;
    #pragma unroll
    for (int q = 0; q < 9; ++q) { float v = p[q]; acc += v*v; }
    wsq[g] = acc;
  }
}

// dm[b][o] = cs * rsqrt(cs^2 * sum_ci s^2 * wsq + 1e-8)   (cs folded for epilogue)
__global__ void k_demod(const float* __restrict__ s, const float* __restrict__ wsq,
                        float* __restrict__ dm) {
  __shared__ float s2[512];
  const int g = blockIdx.x * 256 + threadIdx.x;
  const int b = g >> 9, o = g & 511, t = threadIdx.x;
  float v0 = s[b*512 + t], v1 = s[b*512 + t + 256];
  s2[t] = v0*v0; s2[t+256] = v1*v1;
  __syncthreads();
  const float* row = wsq + (size_t)o * 512;
  float acc = 0.f;
  for (int j = 0; j < 512; ++j) acc += s2[j] * row[j];
  dm[g] = 0.014731391274719739f * rsqrtf(acc * (1.0f/4608.0f) + 1e-8f);
}

// ib[b][cb][y][x][64ci] = bf16(s[b][ci] * in[b][ci][y][x]).
// Coalesced reads (wave = one c8 group), LDS-staged transpose, one 8KB store/block.
__global__ void k_inprep(const float* __restrict__ in, const float* __restrict__ s,
                         unsigned short* __restrict__ ib) {
  __shared__ __align__(16) unsigned char lds[8192];
  const int tid = threadIdx.x;
  const int x = tid & 63, c8 = tid >> 6;
  const int y = blockIdx.x, cb = blockIdx.y, b = blockIdx.z;
  const int ci0 = cb*64 + c8*8;
  f32x4 s0 = *(const f32x4*)(s + b*512 + ci0);
  f32x4 s1 = *(const f32x4*)(s + b*512 + ci0 + 4);
  const float* p = in + (((size_t)b*512 + ci0) * 64 + y) * 64 + x;
  u16x8 h;
  #pragma unroll
  for (int e = 0; e < 4; ++e) h[e]     = f2bf(p[(size_t)e * 4096] * s0[e]);
  #pragma unroll
  for (int e = 0; e < 4; ++e) h[e + 4] = f2bf(p[(size_t)(e + 4) * 4096] * s1[e]);
  *(u16x8*)(lds + x*128 + (((unsigned)(c8*16)) ^ ((unsigned)(x & 7) << 4))) = h;
  __syncthreads();
  const int rx = tid >> 3, rc = tid & 7;
  u16x8 v = *(const u16x8*)(lds + rx*128 + (((unsigned)(rc*16)) ^ ((unsigned)(rx & 7) << 4)));
  unsigned short* dst = ib + (((size_t)(b*8 + cb)*64 + y) * 4096) + tid*8;
  *(u16x8*)dst = v;
}

// ---------------- conv kernel (r11-r13 proven: 128.3us, MfmaUtil 51-53%) ----------------
// 16x16x32 MFMA (the conflict-free shape for this swizzle family -- r18's 32x32
// variant measured 1.4e7 bank conflicts and regressed). B-operand pre-scaled bf16
// from ib; weights batch-independent (4.7MB, L2-shared); cs*demod fenced epilogue.
// 256 blocks (1/CU), 512 threads = 8 waves (2m x 4n), wave tile 128o x 64px.
// LDS: A 3x32KB (dist-2 prefetch, tap t -> buf t%3), B 48KB (per cb).
// 4-barrier tap (PH4), counted GATE(8), full drain only at cb boundary.
__global__ __launch_bounds__(512, 2) void k_conv(const unsigned short* __restrict__ ib,
                                                 const unsigned short* __restrict__ wp,
                                                 const float* __restrict__ dm,
                                                 float* __restrict__ out) {
  __shared__ __align__(16) unsigned char ldsA[3*32768];
  __shared__ __align__(16) unsigned char ldsB[49152];

  const int tid = threadIdx.x;
  const int lan15 = tid & 15;
  const int lgrp = (tid >> 4) & 3;
  const int wid = tid >> 6;
  const int wm = wid >> 2, wn = wid & 3;
  const unsigned wg = blockIdx.x;
  const int b = wg & 7, pt = (wg >> 3) & 15, ot = (wg >> 7) & 1;   // batch b -> one XCD
  const int o0 = ot * 256, y0 = pt * 4;

  const unsigned short* ibb = ib + (size_t)b * 8 * 64 * 64 * 64;

  auto stageA = [&](int tap, int cbb, int buf) {
    const char* src = (const char*)(wp + (((size_t)tap*8 + cbb)*512 + (size_t)o0) * 64);
    unsigned char* dst = ldsA + buf*32768;
    #pragma unroll
    for (int r = 0; r < 4; ++r) {
      __builtin_amdgcn_global_load_lds(
        (const __attribute__((address_space(1))) unsigned int*)(src + tid*16 + r*8192),
        (__attribute__((address_space(3))) unsigned int*)(dst + tid*16 + r*8192),
        16, 0, 0);
    }
  };

  u16x8 bv[6];
  auto loadB = [&](int cbb) {           // 6 x 16B loads/thread (rows clamped)
    const int c8 = tid & 7, x = (tid >> 3) & 63;
    const unsigned short* base = ibb + ((size_t)cbb * 64 * 64 + (size_t)x) * 64 + c8*8;
    #pragma unroll
    for (int j = 0; j < 6; ++j) {
      const int yi = y0 - 1 + j;
      const int yc = yi < 0 ? 0 : (yi > 63 ? 63 : yi);
      bv[j] = *(const u16x8*)(base + (size_t)yc * 4096);
    }
  };
  auto writeB = [&]() {
    const int c8 = tid & 7, x = (tid >> 3) & 63;
    const unsigned off = (unsigned)(x*128) + (((unsigned)(c8*16)) ^ ((unsigned)(x & 7) << 4));
    #pragma unroll
    for (int j = 0; j < 6; ++j) {
      const int yi = y0 - 1 + j;
      const bool valid = (yi >= 0) & (yi < 64);
      u16x8 v = valid ? bv[j] : (u16x8){0,0,0,0,0,0,0,0};
      *(u16x8*)(ldsB + j*8192 + off) = v;
    }
  };

  f32x4 acc[8][4];
  #pragma unroll
  for (int mf = 0; mf < 8; ++mf)
    #pragma unroll
    for (int nf = 0; nf < 4; ++nf)
      acc[mf][nf] = (f32x4){0.f, 0.f, 0.f, 0.f};

  const int aB0 = (wm*128 + lan15)*128 + ((lgrp*16) ^ ((lan15 & 7) << 4));
  const int aB1 = aB0 ^ 64;
  int cB0[3], cB1[3];
  #pragma unroll
  for (int kx = 0; kx < 3; ++kx) {
    const int x0 = lan15 + kx - 1;
    cB0[kx] = wn*8192 + x0*128 + ((lgrp*16) ^ ((x0 & 7) << 4));
    cB1[kx] = cB0[kx] ^ 64;
  }
  const bool zL = (lan15 == 0), zR = (lan15 == 15);

#define BARR asm volatile("s_barrier" ::: "memory")
#define GATE(N) asm volatile("s_waitcnt vmcnt(" #N ")\n\ts_barrier" ::: "memory")

#define RD_A(MH, KS) _Pragma("unroll") \
    for (int i = 0; i < 4; ++i) \
      af[i] = *(const bf16x8*)(Ab + ((KS) ? aB1 : aB0) + ((MH)*4 + i)*2048);

#define RD_B(KS) _Pragma("unroll") \
    for (int nf = 0; nf < 4; ++nf) { \
      bf16x8 v = *(const bf16x8*)(Bb + ((KS) ? cB1[kx_] : cB0[kx_]) + nf*2048); \
      if (kx_ == 0 && nf == 0) { if (zL) v = (bf16x8){0,0,0,0,0,0,0,0}; } \
      if (kx_ == 2 && nf == 3) { if (zR) v = (bf16x8){0,0,0,0,0,0,0,0}; } \
      bfr[nf] = v; }

#define MF16(MH) { __builtin_amdgcn_s_setprio(1); \
    _Pragma("unroll") for (int i = 0; i < 4; ++i) \
      _Pragma("unroll") for (int nf = 0; nf < 4; ++nf) \
        acc[(MH)*4+i][nf] = __builtin_amdgcn_mfma_f32_16x16x32_bf16(af[i], bfr[nf], acc[(MH)*4+i][nf], 0, 0, 0); \
    __builtin_amdgcn_s_setprio(0); }

// 4 barrier intervals: {rdA0,rdB0 | MF0 rdA1 | MF1 rdA0' rdB1 | MF0' rdA1' | MF1'}
#define PH4 \
    RD_A(0,0) RD_B(0) MF16(0) \
    RD_A(1,0) BARR; MF16(1) \
    RD_A(0,1) RD_B(1) BARR; MF16(0) \
    RD_A(1,1) BARR; MF16(1)

#define TAP(KK) { \
    constexpr int ky_ = (KK)/3, kx_ = (KK)%3; \
    const unsigned char* Ab = ldsA + ((KK)%3)*32768; \
    const unsigned char* Bb = ldsB + ky_*8192; \
    bf16x8 af[4], bfr[4]; \
    stageA((KK)+2, cb, ((KK)+2)%3); \
    GATE(8); \
    PH4 }

  // prologue: B0 loads, A0+A1 in flight, write B0, gated barrier.
  loadB(0);
  asm volatile("" ::: "memory");
  stageA(0, 0, 0);
  stageA(1, 0, 1);
  asm volatile("s_waitcnt vmcnt(8)" ::: "memory");   // B(6) done; A0/A1 in flight
  writeB();
  asm volatile("s_waitcnt vmcnt(4) lgkmcnt(0)\n\ts_barrier" ::: "memory");  // A0 done

  for (int cb = 0; cb < 7; ++cb) {
    TAP(0) TAP(1) TAP(2) TAP(3) TAP(4) TAP(5) TAP(6)
    { // kk == 7: stage A(next-cb,0), gate, issue B loads, phases
      constexpr int ky_ = 2, kx_ = 1;
      const unsigned char* Ab = ldsA + (7%3)*32768;
      const unsigned char* Bb = ldsB + ky_*8192;
      bf16x8 af[4], bfr[4];
      stageA(0, cb + 1, 0);
      GATE(8);
      loadB(cb + 1);
      PH4
    }
    { // kk == 8: drain (B + A(8)), stage A(next,1), phases, boundary write
      asm volatile("s_waitcnt vmcnt(0)" ::: "memory");
      stageA(1, cb + 1, 1);
      constexpr int ky_ = 2, kx_ = 2;
      const unsigned char* Ab = ldsA + (8%3)*32768;
      const unsigned char* Bb = ldsB + ky_*8192;
      bf16x8 af[4], bfr[4];
      PH4
      BARR;                                          // all waves done reading B(cb)
      writeB();
      asm volatile("s_waitcnt lgkmcnt(0)\n\ts_barrier" ::: "memory");
    }
  }
  { // cb == 7 tail
    const int cb = 7;
    TAP(0) TAP(1) TAP(2) TAP(3) TAP(4) TAP(5) TAP(6)
    { // kk == 7: no staging left; gate on A(8) in flight
      constexpr int ky_ = 2, kx_ = 1;
      const unsigned char* Ab = ldsA + (7%3)*32768;
      const unsigned char* Bb = ldsB + ky_*8192;
      bf16x8 af[4], bfr[4];
      GATE(4);
      PH4
    }
    { // kk == 8: final drain
      asm volatile("s_waitcnt vmcnt(0)" ::: "memory");
      constexpr int ky_ = 2, kx_ = 2;
      const unsigned char* Ab = ldsA + (8%3)*32768;
      const unsigned char* Bb = ldsB + ky_*8192;
      bf16x8 af[4], bfr[4];
      PH4
    }
  }

  // epilogue: scale by cs*demod[b][o], fenced per-mf (one d4 live at a time)
  const float* dmb = dm + b*512;
  float* outb = out + (size_t)b * 512 * 4096;
  #pragma unroll
  for (int mf = 0; mf < 8; ++mf) {
    asm volatile("" ::: "memory");     // pin d4 load into this iteration
    const int o = o0 + wm*128 + mf*16 + lgrp*4;
    const f32x4 d4 = *(const f32x4*)(dmb + o);
    #pragma unroll
    for (int nf = 0; nf < 4; ++nf) {
      const int p = pt*256 + wn*64 + nf*16 + lan15;
      #pragma unroll
      for (int r = 0; r < 4; ++r)
        outb[(size_t)(o + r) * 4096 + p] = acc[mf][nf][r] * d4[r];
    }
  }
#undef TAP
#undef PH4
#undef MF16
#undef RD_B
#undef RD_A
#undef GATE
#undef BARR
}

extern "C" void kernel_launch(void* const* d_in, const int* in_sizes, int n_in,
                              void* d_out, int out_size, void* d_ws, size_t ws_size,
                              hipStream_t stream) {
  const float* input  = (const float*)d_in[0];
  const float* style  = (const float*)d_in[1];
  const float* weight = (const float*)d_in[2];
  const float* mw     = (const float*)d_in[3];
  const float* mb     = (const float*)d_in[4];
  float* out = (float*)d_out;
  char* ws = (char*)d_ws;
  float* s     = (float*)ws;                              // 16 KB
  float* dm    = (float*)(ws + 16384);                    // 16 KB
  float* wsq   = (float*)(ws + 32768);                    // 1 MB
  unsigned short* wp = (unsigned short*)(ws + 1081344);   // 4.7 MB (batch-independent)
  unsigned short* ib = (unsigned short*)(ws + 5799936);   // 33.6 MB (pre-scaled bf16 input)

  hipLaunchKernelGGL(k1,       dim3(2184),      dim3(256), 0, stream, weight, style, mw, mb, wp, s, wsq);
  hipLaunchKernelGGL(k_demod,  dim3(16),        dim3(256), 0, stream, s, wsq, dm);
  hipLaunchKernelGGL(k_inprep, dim3(64, 8, 8),  dim3(512), 0, stream, input, s, ib);
  hipLaunchKernelGGL(k_conv,   dim3(256),       dim3(512), 0, stream, ib, wp, dm, out);
}